// Round 11
// baseline (253.894 us; speedup 1.0000x reference)
//
#include <hip/hip_runtime.h>
#include <hip/hip_bf16.h>

// Problem constants (from reference)
#define T_DIM   16
#define N_NODES 10000
#define FIN     32
#define FH      64
#define NE      160000
#define TB      4              // timesteps per chunk
#define NCHUNK  (T_DIM / TB)   // 4 chunks
#define NF      (N_NODES * FIN)
#define RECQ    33             // float4s per node record (32 data + 1 pad)
#define GPB     16             // 32-lane groups per 512-thread block

// ---------------------------------------------------------------------------
// Kernel 1 (merged): blocks 0..4999 transpose x -> xp4; blocks 5000..5624
// degree histogram + per-edge slot.
// xp4[tc][n*RECQ + f] = float4{ x[tc*4+k][n][f] : k=0..3 }
// ---------------------------------------------------------------------------
__global__ __launch_bounds__(256) void prep_kernel(
    const float* __restrict__ x, float4* __restrict__ xp4,
    const int* __restrict__ ei, const float* __restrict__ w,
    float* __restrict__ deg, int* __restrict__ cnt, int* __restrict__ slot) {
    int b = blockIdx.x;
    int tid = threadIdx.x;
    if (b < 5000) {
        int tc = b & 3;
        int nb = b >> 2;                 // 0..1249
        int f = tid & 31, ns = tid >> 5; // 8 nodes per block
        int n = nb * 8 + ns;
        const float* xb = x + (size_t)(tc * TB) * NF + n * FIN + f;
        float4 v = make_float4(xb[0], xb[NF], xb[2 * NF], xb[3 * NF]);
        xp4[(size_t)tc * (N_NODES * RECQ) + n * RECQ + f] = v;
    } else {
        int e = (b - 5000) * 256 + tid;
        if (e < NE) {
            int d = ei[NE + e];          // dst row of edge_index (2, E)
            atomicAdd(&deg[d], w[e]);
            slot[e] = atomicAdd(&cnt[d], 1);
        }
    }
}

// ---------------------------------------------------------------------------
// Kernel 2: blocks 0-9 dis/selfnorm; block 10 exclusive scan; blocks 11-12
// pack W1/W2 into per-lane float2 column pairs.
// W1p[f*32+l] = {W1[f][l], W1[f][l+32]}   (f<32, l<32)
// W2p[j*32+l] = {W2[j][l], W2[j+32][l]}   (j<32, l<32)
// ---------------------------------------------------------------------------
__global__ __launch_bounds__(1024) void mid_kernel(
    const float* __restrict__ deg, float* __restrict__ dis,
    float* __restrict__ selfn,
    const int* __restrict__ cnt, int* __restrict__ rowptr,
    const float* __restrict__ W1, const float* __restrict__ W2,
    float2* __restrict__ W1p, float2* __restrict__ W2p) {
    __shared__ int sm[1024];
    int b = blockIdx.x;
    int tid = threadIdx.x;
    if (b < 10) {                        // dis / selfnorm
        int n = b * 1024 + tid;
        if (n < N_NODES) {
            float d = deg[n] + 1.0f;     // + self-loop weight
            float r = rsqrtf(d);
            dis[n] = r;
            selfn[n] = r * r;
        }
    } else if (b == 10) {                // exclusive scan
        int base = tid * 10;
        int v[10];
        int s = 0;
#pragma unroll
        for (int k = 0; k < 10; ++k) {
            int i = base + k;
            v[k] = (i < N_NODES) ? cnt[i] : 0;
            s += v[k];
        }
        sm[tid] = s;
        __syncthreads();
        for (int off = 1; off < 1024; off <<= 1) {
            int t = (tid >= off) ? sm[tid - off] : 0;
            __syncthreads();
            sm[tid] += t;
            __syncthreads();
        }
        int run = (tid > 0) ? sm[tid - 1] : 0;
#pragma unroll
        for (int k = 0; k < 10; ++k) {
            int i = base + k;
            if (i <= N_NODES) rowptr[i] = run;
            run += v[k];
        }
    } else if (b == 11) {
        int f = tid >> 5, l = tid & 31;
        W1p[tid] = make_float2(W1[f * FH + l], W1[f * FH + 32 + l]);
    } else {
        int j = tid >> 5, l = tid & 31;
        W2p[tid] = make_float2(W2[j * FIN + l], W2[(j + 32) * FIN + l]);
    }
}

// ---------------------------------------------------------------------------
// Kernel 3: scatter edges into dst-sorted CSR, packed {col, norm-bits}
// ---------------------------------------------------------------------------
__global__ void build_csr_kernel(const int* __restrict__ ei,
                                 const float* __restrict__ w,
                                 const float* __restrict__ dis,
                                 const int* __restrict__ rowptr,
                                 const int* __restrict__ slot,
                                 int2* __restrict__ edges) {
    int e = blockIdx.x * blockDim.x + threadIdx.x;
    if (e < NE) {
        int s = ei[e];
        int d = ei[NE + e];
        int pos = rowptr[d] + slot[e];
        edges[pos] = make_int2(s, __float_as_int(dis[s] * w[e] * dis[d]));
    }
}

// float4 gather step: acc[0..3] += val * Q[col*RECQ]  (Q pre-offset by lane)
#define GF4(P, Q) { float4 q = Q[(size_t)(P).x * RECQ];                     \
                    float vv = __int_as_float((P).y);                       \
                    a0 = fmaf(vv, q.x, a0); a1 = fmaf(vv, q.y, a1);         \
                    a2 = fmaf(vv, q.z, a2); a3 = fmaf(vv, q.w, a3); }

#define GATHER4(Q)                                                          \
    for (; e + 4 <= e1; e += 4) {                                           \
        int2 p0 = edges[e], p1 = edges[e + 1];                              \
        int2 p2 = edges[e + 2], p3 = edges[e + 3];                          \
        GF4(p0, Q) GF4(p1, Q) GF4(p2, Q) GF4(p3, Q)                         \
    }                                                                       \
    for (; e < e1; ++e) { int2 p = edges[e]; GF4(p, Q) }

// ---------------------------------------------------------------------------
// Kernel 4 (fused layer 1): TB=4. One 32-lane group per node; lane = f.
// Gather: ONE float4 load per edge (528 B padded node records -> full
// L1-set spread). Requests halved vs TB=2. Dense: r8's proven float2
// pipeline run twice (t0/t1 then t2/t3); weights LDS-staged, single
// barrier after staging; sAcc/sH wave-private (no further barriers).
// ---------------------------------------------------------------------------
__global__ __launch_bounds__(512) void layer1_kernel(
    const float4* __restrict__ xp4,
    const int* __restrict__ rowptr,
    const int2* __restrict__ edges,
    const float* __restrict__ selfn,
    const float2* __restrict__ W1p,
    const float* __restrict__ b1,
    const float2* __restrict__ W2p,
    float4* __restrict__ gp4) {
    __shared__ float2 sW1p[FIN * 32];       // 8 KB
    __shared__ float2 sW2p[32 * FIN];       // 8 KB
    __shared__ float sB1[FH];               // 256 B
    __shared__ float2 sAcc[GPB][FIN];       // 4 KB
    __shared__ float sH[GPB][TB / 2][FH];   // 8 KB

    int tid = threadIdx.x;
    sW1p[tid] = W1p[tid];
    sW1p[tid + 512] = W1p[tid + 512];
    sW2p[tid] = W2p[tid];
    sW2p[tid + 512] = W2p[tid + 512];
    if (tid < FH) sB1[tid] = b1[tid];
    __syncthreads();                        // staging visible; groups decouple

    int bck = blockIdx.x;
    int tc = bck & 3;
    int nb = bck >> 2;
    int grp = tid >> 5;
    int lane = tid & 31;
    int n = nb * GPB + grp;

    const float4* xq = xp4 + (size_t)tc * (N_NODES * RECQ) + lane;

    float sn = selfn[n];
    float4 xs = xq[(size_t)n * RECQ];
    float a0 = sn * xs.x, a1 = sn * xs.y, a2 = sn * xs.z, a3 = sn * xs.w;

    int e = rowptr[n], e1 = rowptr[n + 1];
    GATHER4(xq)

    // ---- dense, two rounds (t0,t1) then (t2,t3); wave-private LDS ----
    float gt0, gt1, gt2, gt3;
#pragma unroll
    for (int r = 0; r < 2; ++r) {
        float aA = (r == 0) ? a0 : a2;
        float aB = (r == 0) ? a1 : a3;
        sAcc[grp][lane] = make_float2(aA, aB);
        float h0 = sB1[lane];
        float h1 = sB1[lane + 32];
        float h2 = h0, h3 = h1;
#pragma unroll
        for (int f = 0; f < FIN; ++f) {
            float2 w = sW1p[f * 32 + lane];
            float2 af = sAcc[grp][f];       // same-wave LDS broadcast
            h0 = fmaf(af.x, w.x, h0); h1 = fmaf(af.x, w.y, h1);
            h2 = fmaf(af.y, w.x, h2); h3 = fmaf(af.y, w.y, h3);
        }
        sH[grp][0][lane] = fmaxf(h0, 0.0f);
        sH[grp][0][lane + 32] = fmaxf(h1, 0.0f);
        sH[grp][1][lane] = fmaxf(h2, 0.0f);
        sH[grp][1][lane + 32] = fmaxf(h3, 0.0f);
        float g0 = 0.0f, g1 = 0.0f;
#pragma unroll
        for (int j = 0; j < 32; ++j) {
            float2 w = sW2p[j * 32 + lane];
            g0 = fmaf(sH[grp][0][j], w.x, g0);
            g0 = fmaf(sH[grp][0][j + 32], w.y, g0);
            g1 = fmaf(sH[grp][1][j], w.x, g1);
            g1 = fmaf(sH[grp][1][j + 32], w.y, g1);
        }
        if (r == 0) { gt0 = g0; gt1 = g1; } else { gt2 = g0; gt3 = g1; }
    }
    gp4[(size_t)tc * (N_NODES * RECQ) + n * RECQ + lane] =
        make_float4(gt0, gt1, gt2, gt3);
}

// ---------------------------------------------------------------------------
// Kernel 5 (layer 2 aggregation): same TB=4 structure; one float4 load per
// edge from gp4; 4 coalesced output stores + b2.
// ---------------------------------------------------------------------------
__global__ __launch_bounds__(512) void layer2_kernel(
    const float4* __restrict__ gp4,
    const int* __restrict__ rowptr,
    const int2* __restrict__ edges,
    const float* __restrict__ selfn,
    const float* __restrict__ b2,
    float* __restrict__ out, int out_size) {
    int bck = blockIdx.x;
    int tc = bck & 3;
    int nb = bck >> 2;
    int tid = threadIdx.x;
    int grp = tid >> 5;
    int lane = tid & 31;
    int n = nb * GPB + grp;

    const float4* gq = gp4 + (size_t)tc * (N_NODES * RECQ) + lane;

    float sn = selfn[n];
    float bb = b2[lane];
    float4 gs = gq[(size_t)n * RECQ];
    float a0 = fmaf(sn, gs.x, bb), a1 = fmaf(sn, gs.y, bb);
    float a2 = fmaf(sn, gs.z, bb), a3 = fmaf(sn, gs.w, bb);

    int e = rowptr[n], e1 = rowptr[n + 1];
    GATHER4(gq)

    float* ob = out + (size_t)(tc * TB) * NF + n * FIN + lane;
    ob[0] = a0;
    ob[NF] = a1;
    ob[2 * NF] = a2;
    ob[3 * NF] = a3;

    // second tuple element (scalar 0) and any tail
    if (bck == 0 && tid == 0) {
        for (int i = T_DIM * NF; i < out_size; ++i) out[i] = 0.0f;
    }
}

// ---------------------------------------------------------------------------
extern "C" void kernel_launch(void* const* d_in, const int* in_sizes, int n_in,
                              void* d_out, int out_size, void* d_ws, size_t ws_size,
                              hipStream_t stream) {
    const float* x  = (const float*)d_in[0];
    const int*   ei = (const int*)d_in[1];     // (2, E) int32: [src | dst]
    const float* w  = (const float*)d_in[2];
    // d_in[3] missing_mask: unused by reference math
    const float* W1 = (const float*)d_in[4];
    const float* b1 = (const float*)d_in[5];
    const float* W2 = (const float*)d_in[6];
    const float* b2 = (const float*)d_in[7];
    float* out = (float*)d_out;

    char* p = (char*)d_ws;
    float4* xp4   = (float4*)p; p += sizeof(float4) * (size_t)N_NODES * RECQ * NCHUNK;
    float4* gp4   = (float4*)p; p += sizeof(float4) * (size_t)N_NODES * RECQ * NCHUNK;
    // deg, cnt contiguous -> single memset
    float* deg    = (float*)p; p += sizeof(float) * N_NODES;
    int*   cnt    = (int*)p;   p += sizeof(int) * N_NODES;
    float* dis    = (float*)p; p += sizeof(float) * N_NODES;
    float* selfn  = (float*)p; p += sizeof(float) * N_NODES;
    int*   rowptr = (int*)p;   p += sizeof(int) * (N_NODES + 1);
    int*   slot   = (int*)p;   p += sizeof(int) * NE;
    int2*  edges  = (int2*)p;  p += sizeof(int2) * NE;
    float2* W1p   = (float2*)p; p += sizeof(float2) * FIN * 32;
    float2* W2p   = (float2*)p; p += sizeof(float2) * 32 * FIN;

    hipMemsetAsync(deg, 0, sizeof(float) * N_NODES * 2, stream);

    prep_kernel<<<5000 + (NE + 255) / 256, 256, 0, stream>>>(
        x, xp4, ei, w, deg, cnt, slot);
    mid_kernel<<<13, 1024, 0, stream>>>(deg, dis, selfn, cnt, rowptr,
                                        W1, W2, W1p, W2p);
    build_csr_kernel<<<(NE + 255) / 256, 256, 0, stream>>>(ei, w, dis, rowptr,
                                                           slot, edges);
    layer1_kernel<<<(N_NODES / GPB) * NCHUNK, 512, 0, stream>>>(
        xp4, rowptr, edges, selfn, W1p, b1, W2p, gp4);
    layer2_kernel<<<(N_NODES / GPB) * NCHUNK, 512, 0, stream>>>(
        gp4, rowptr, edges, selfn, b2, out, out_size);
}

// Round 12
// 224.257 us; speedup vs baseline: 1.1322x; 1.1322x over previous
//
#include <hip/hip_runtime.h>
#include <hip/hip_bf16.h>

// Problem constants (from reference)
#define T_DIM   16
#define N_NODES 10000
#define FIN     32
#define FH      64
#define NE      160000
#define TB      2              // timesteps per chunk
#define NCHUNK  (T_DIM / TB)   // 8 chunks -> one per XCD via bid%8
#define NF      (N_NODES * FIN)
#define REC     64             // floats per node record: 2 t-halves x 32 f
#define WPB     8              // waves (nodes) per 512-thread block

// ---------------------------------------------------------------------------
// Kernel 1 (merged): blocks 0..19999 transpose x -> xpN (uniform-wave layout,
// XCD-pinned: writer bid%8 == consumer tc); blocks 20000..20624 degree
// histogram + per-edge slot.
// xpN[tc][n*64 + th*32 + f] = x[tc*2+th][n][f]
// ---------------------------------------------------------------------------
__global__ __launch_bounds__(256) void prep_kernel(
    const float* __restrict__ x, float* __restrict__ xpN,
    const int* __restrict__ ei, const float* __restrict__ w,
    float* __restrict__ deg, int* __restrict__ cnt, int* __restrict__ slot) {
    int b = blockIdx.x;
    int tid = threadIdx.x;
    if (b < 20000) {
        int tc = b & 7;
        int nb = b >> 3;                 // 0..2499
        int f = tid & 31, th = (tid >> 5) & 1, ns = tid >> 6;
        int n = nb * 4 + ns;
        xpN[(size_t)tc * (N_NODES * REC) + n * REC + th * 32 + f] =
            x[(size_t)(tc * TB + th) * NF + n * FIN + f];
    } else {
        int e = (b - 20000) * 256 + tid;
        if (e < NE) {
            int d = ei[NE + e];          // dst row of edge_index (2, E)
            atomicAdd(&deg[d], w[e]);
            slot[e] = atomicAdd(&cnt[d], 1);
        }
    }
}

// ---------------------------------------------------------------------------
// Kernel 2: blocks 0-9 dis/selfnorm; block 10 exclusive scan cnt -> rowptr
// ---------------------------------------------------------------------------
__global__ __launch_bounds__(1024) void mid_kernel(
    const float* __restrict__ deg, float* __restrict__ dis,
    float* __restrict__ selfn,
    const int* __restrict__ cnt, int* __restrict__ rowptr) {
    __shared__ int sm[1024];
    int b = blockIdx.x;
    int tid = threadIdx.x;
    if (b < 10) {                        // dis / selfnorm
        int n = b * 1024 + tid;
        if (n < N_NODES) {
            float d = deg[n] + 1.0f;     // + self-loop weight
            float r = rsqrtf(d);
            dis[n] = r;
            selfn[n] = r * r;
        }
    } else {                             // exclusive scan
        int base = tid * 10;
        int v[10];
        int s = 0;
#pragma unroll
        for (int k = 0; k < 10; ++k) {
            int i = base + k;
            v[k] = (i < N_NODES) ? cnt[i] : 0;
            s += v[k];
        }
        sm[tid] = s;
        __syncthreads();
        for (int off = 1; off < 1024; off <<= 1) {
            int t = (tid >= off) ? sm[tid - off] : 0;
            __syncthreads();
            sm[tid] += t;
            __syncthreads();
        }
        int run = (tid > 0) ? sm[tid - 1] : 0;
#pragma unroll
        for (int k = 0; k < 10; ++k) {
            int i = base + k;
            if (i <= N_NODES) rowptr[i] = run;
            run += v[k];
        }
    }
}

// ---------------------------------------------------------------------------
// Kernel 3: scatter edges into dst-sorted CSR, packed {col, norm-bits}
// ---------------------------------------------------------------------------
__global__ void build_csr_kernel(const int* __restrict__ ei,
                                 const float* __restrict__ w,
                                 const float* __restrict__ dis,
                                 const int* __restrict__ rowptr,
                                 const int* __restrict__ slot,
                                 int2* __restrict__ edges) {
    int e = blockIdx.x * blockDim.x + threadIdx.x;
    if (e < NE) {
        int s = ei[e];
        int d = ei[NE + e];
        int pos = rowptr[d] + slot[e];
        edges[pos] = make_int2(s, __float_as_int(dis[s] * w[e] * dis[d]));
    }
}

// Uniform-wave CSR gather: acc += val * src[col*REC + l]; everything except
// the gathered value is wave-uniform (scalar pipe / 1-address loads).
#define GATHER(Q)                                                           \
    for (; e + 4 <= e1; e += 4) {                                           \
        int2 p0 = edges[e], p1 = edges[e + 1];                              \
        int2 p2 = edges[e + 2], p3 = edges[e + 3];                          \
        float q0 = Q[p0.x * REC + l], q1 = Q[p1.x * REC + l];               \
        float q2 = Q[p2.x * REC + l], q3 = Q[p3.x * REC + l];               \
        acc = fmaf(__int_as_float(p0.y), q0, acc);                          \
        acc = fmaf(__int_as_float(p1.y), q1, acc);                          \
        acc = fmaf(__int_as_float(p2.y), q2, acc);                          \
        acc = fmaf(__int_as_float(p3.y), q3, acc);                          \
    }                                                                       \
    for (; e < e1; ++e) {                                                   \
        int2 p = edges[e];                                                  \
        acc = fmaf(__int_as_float(p.y), Q[p.x * REC + l], acc);             \
    }

// ---------------------------------------------------------------------------
// Kernel 4 (fused layer 1): ONE WAVE PER NODE (lane = f + 32*th), TB=2.
// blockIdx = nb*8 + tc pins chunk->XCD (xpN slice 2.56 MB, L2-resident).
// Gather: 1 dword load + 1 fmac per lane per edge, uniform control flow.
// Dense: h[j=l] for both t (shared weight reg), then g[k=l&31, t=l>>5].
// Weights LDS-staged; only barrier is after staging; sAcc/sH wave-private.
// ---------------------------------------------------------------------------
__global__ __launch_bounds__(512) void layer1_kernel(
    const float* __restrict__ xpN,
    const int* __restrict__ rowptr,
    const int2* __restrict__ edges,
    const float* __restrict__ selfn,
    const float* __restrict__ W1,
    const float* __restrict__ b1,
    const float* __restrict__ W2,
    float* __restrict__ gpN) {
    __shared__ float sW1[FIN * FH];            // 8 KB  [f*64 + j]
    __shared__ float sW2[FH * FIN];            // 8 KB  [j*32 + k]
    __shared__ float sB1[FH];                  // 256 B
    __shared__ float2 sAcc2[WPB][FIN];         // 2 KB  [w][f] = {t0, t1}
    __shared__ float2 sH2[WPB][TB][FH / 2];    // 4 KB  [w][t][j/2]

    int tid = threadIdx.x;
    for (int i = tid; i < FIN * FH; i += 512) sW1[i] = W1[i];
    for (int i = tid; i < FH * FIN; i += 512) sW2[i] = W2[i];
    if (tid < FH) sB1[tid] = b1[tid];
    __syncthreads();                           // staging visible; waves decouple

    int bck = blockIdx.x;
    int tc = bck & 7;
    int nb = bck >> 3;
    int wv = __builtin_amdgcn_readfirstlane(tid >> 6);
    int l = tid & 63;
    int n = nb * WPB + wv;

    const float* xq = xpN + (size_t)tc * (N_NODES * REC);

    float acc = selfn[n] * xq[n * REC + l];
    int e = rowptr[n], e1 = rowptr[n + 1];
    GATHER(xq)

    // ---- dense (wave-private, no barriers) ----
    int f = l & 31, th = l >> 5;
    ((float*)&sAcc2[wv][f])[th] = acc;

    float h0 = sB1[l];                         // j = l, t0
    float h1 = h0;                             // j = l, t1
#pragma unroll
    for (int ff = 0; ff < FIN; ++ff) {
        float2 af = sAcc2[wv][ff];             // broadcast {t0, t1}
        float wj = sW1[ff * FH + l];
        h0 = fmaf(af.x, wj, h0);
        h1 = fmaf(af.y, wj, h1);
    }
    float* ph = (float*)sH2[wv];               // [0..63]=t0, [64..127]=t1
    ph[l] = fmaxf(h0, 0.0f);
    ph[64 + l] = fmaxf(h1, 0.0f);

    float g = 0.0f;                            // k = f, t = th
#pragma unroll
    for (int j2 = 0; j2 < FH / 2; ++j2) {
        float2 hh = sH2[wv][th][j2];           // 2-address broadcast
        g = fmaf(hh.x, sW2[(2 * j2) * FIN + f], g);
        g = fmaf(hh.y, sW2[(2 * j2 + 1) * FIN + f], g);
    }
    gpN[(size_t)tc * (N_NODES * REC) + n * REC + l] = g;
}

// ---------------------------------------------------------------------------
// Kernel 5 (layer 2 aggregation): same uniform-wave structure, no LDS.
// gpN slice written by the same XCD in layer1 -> L2-local. out (T,N,F) + b2.
// ---------------------------------------------------------------------------
__global__ __launch_bounds__(512) void layer2_kernel(
    const float* __restrict__ gpN,
    const int* __restrict__ rowptr,
    const int2* __restrict__ edges,
    const float* __restrict__ selfn,
    const float* __restrict__ b2,
    float* __restrict__ out, int out_size) {
    int bck = blockIdx.x;
    int tc = bck & 7;
    int nb = bck >> 3;
    int tid = threadIdx.x;
    int wv = __builtin_amdgcn_readfirstlane(tid >> 6);
    int l = tid & 63;
    int n = nb * WPB + wv;
    int f = l & 31, th = l >> 5;

    const float* gq = gpN + (size_t)tc * (N_NODES * REC);

    float acc = b2[f] + selfn[n] * gq[n * REC + l];
    int e = rowptr[n], e1 = rowptr[n + 1];
    GATHER(gq)

    out[(size_t)(tc * TB + th) * NF + n * FIN + f] = acc;

    // second tuple element (scalar 0) and any tail
    if (bck == 0 && tid == 0) {
        for (int i = T_DIM * NF; i < out_size; ++i) out[i] = 0.0f;
    }
}

// ---------------------------------------------------------------------------
extern "C" void kernel_launch(void* const* d_in, const int* in_sizes, int n_in,
                              void* d_out, int out_size, void* d_ws, size_t ws_size,
                              hipStream_t stream) {
    const float* x  = (const float*)d_in[0];
    const int*   ei = (const int*)d_in[1];     // (2, E) int32: [src | dst]
    const float* w  = (const float*)d_in[2];
    // d_in[3] missing_mask: unused by reference math
    const float* W1 = (const float*)d_in[4];
    const float* b1 = (const float*)d_in[5];
    const float* W2 = (const float*)d_in[6];
    const float* b2 = (const float*)d_in[7];
    float* out = (float*)d_out;

    char* p = (char*)d_ws;
    float* xpN    = (float*)p; p += sizeof(float) * (size_t)N_NODES * REC * NCHUNK;
    float* gpN    = (float*)p; p += sizeof(float) * (size_t)N_NODES * REC * NCHUNK;
    // deg, cnt contiguous -> single memset
    float* deg    = (float*)p; p += sizeof(float) * N_NODES;
    int*   cnt    = (int*)p;   p += sizeof(int) * N_NODES;
    float* dis    = (float*)p; p += sizeof(float) * N_NODES;
    float* selfn  = (float*)p; p += sizeof(float) * N_NODES;
    int*   rowptr = (int*)p;   p += sizeof(int) * (N_NODES + 1);
    int*   slot   = (int*)p;   p += sizeof(int) * NE;
    int2*  edges  = (int2*)p;  p += sizeof(int2) * NE;

    hipMemsetAsync(deg, 0, sizeof(float) * N_NODES * 2, stream);

    prep_kernel<<<20000 + (NE + 255) / 256, 256, 0, stream>>>(
        x, xpN, ei, w, deg, cnt, slot);
    mid_kernel<<<11, 1024, 0, stream>>>(deg, dis, selfn, cnt, rowptr);
    build_csr_kernel<<<(NE + 255) / 256, 256, 0, stream>>>(ei, w, dis, rowptr,
                                                           slot, edges);
    layer1_kernel<<<(N_NODES / WPB) * NCHUNK, 512, 0, stream>>>(
        xpN, rowptr, edges, selfn, W1, b1, W2, gpN);
    layer2_kernel<<<(N_NODES / WPB) * NCHUNK, 512, 0, stream>>>(
        gpN, rowptr, edges, selfn, b2, out, out_size);
}